// Round 14
// baseline (681.803 us; speedup 1.0000x reference)
//
#include <hip/hip_runtime.h>
#include <hip/hip_bf16.h>

typedef __attribute__((ext_vector_type(8))) short short8;
typedef __attribute__((ext_vector_type(4))) float f32x4;

__device__ __forceinline__ unsigned short f2bf(float v) {
    __hip_bfloat16 h = __float2bfloat16(v);   // RNE
    return *reinterpret_cast<unsigned short*>(&h);
}
__device__ __forceinline__ float bf2f(unsigned short u) {
    union { unsigned int i; float f; } x;
    x.i = (unsigned int)u << 16;
    return x.f;
}

constexpr int MAXB = 2048;   // max fine buckets (N/64 = 1563 here)
constexpr int CAP  = 2048;   // slots per bucket; mean load 1024, sd 32 -> safe

// ---------------------------------------------------------------------------
// Weight pre-transpose: Wt[(r*H + h)*64 + d] = bf16( r<R ? W[r][d][h]
//                                                        : Wself[d][h] ).
// With r=R appended, Wt is exactly the K=(R+1)*64=576 concatenated operand
// for the fused layer kernel.
// ---------------------------------------------------------------------------
template<int H>
__global__ __launch_bounds__(256) void transpose_w(
    const float* __restrict__ W, const float* __restrict__ Wself,
    unsigned short* __restrict__ Wt, int R)
{
    int i = blockIdx.x * 256 + threadIdx.x;
    int total = (R + 1) * H * 64;
    if (i >= total) return;
    int d = i & 63;
    int hh = i >> 6;               // r*H + h
    int r = hh / H, h = hh % H;    // H compile-time -> shifts
    float v = (r < R) ? W[((size_t)r * 64 + d) * H + h]
                      : Wself[(size_t)d * H + h];
    Wt[i] = f2bf(v);
}

// ---------------------------------------------------------------------------
// feat fp32 -> bf16 table (one-time, 12.8 MB).
// ---------------------------------------------------------------------------
__global__ __launch_bounds__(256) void f32_to_bf16(
    const float* __restrict__ in, unsigned short* __restrict__ out, int total4)
{
    int i = blockIdx.x * 256 + threadIdx.x;
    if (i >= total4) return;
    float4 v = *(const float4*)&in[(size_t)i * 4];
    ushort4 u;
    u.x = f2bf(v.x); u.y = f2bf(v.y); u.z = f2bf(v.z); u.w = f2bf(v.w);
    *(ushort4*)&out[(size_t)i * 4] = u;
}

// ---------------------------------------------------------------------------
// Bucket partition (single pass, fixed-capacity windows).
// Record: (src << 9) | ((dst & 63) << 3) | et   (src < 2^17 here).
// ---------------------------------------------------------------------------
__global__ __launch_bounds__(256) void zero_int(int* __restrict__ p, int n) {
    int i = blockIdx.x * 256 + threadIdx.x;
    if (i < n) p[i] = 0;
}

__global__ __launch_bounds__(256) void partition_fine(
    const int* __restrict__ src, const int* __restrict__ dst,
    const int* __restrict__ et, int* __restrict__ cnt,
    int* __restrict__ rec, int E, int N, int B, int CH)
{
    __shared__ int hist[MAXB];
    __shared__ int base[MAXB];
    __shared__ int cntl[MAXB];
    const int t = threadIdx.x;
    const int e0 = blockIdx.x * CH, e1 = min(E, e0 + CH);

    for (int i = t; i < B; i += 256) hist[i] = 0;
    __syncthreads();
    for (int e = e0 + t; e < e1; e += 256) atomicAdd(&hist[dst[e] >> 6], 1);
    __syncthreads();
    for (int i = t; i < B; i += 256) {
        int h = hist[i];
        base[i] = h ? atomicAdd(&cnt[i], h) : 0;
        cntl[i] = 0;
    }
    __syncthreads();
    for (int e = e0 + t; e < e1; e += 256) {
        int d = dst[e];
        int b = d >> 6;
        int pos = base[b] + atomicAdd(&cntl[b], 1);
        if (pos < CAP)
            rec[(size_t)b * CAP + pos] = (src[e] << 9) | ((d & 63) << 3) | et[e];
    }
}

// ---------------------------------------------------------------------------
// Per-bucket 512-bin counting sort by cell key (dst&63)*8+et.
// Outputs eidx (src values, grouped by cell) and cell_beg[b*513 + k]
// (absolute offsets into eidx; entry 512 = bucket end).
// ---------------------------------------------------------------------------
__global__ __launch_bounds__(256) void bucket_sort512(
    const int* __restrict__ cnt, const int* __restrict__ rec,
    int* __restrict__ eidx, int* __restrict__ cell_beg)
{
    __shared__ int hist[512];
    __shared__ int ts[256];
    __shared__ int cur[512];
    const int b = blockIdx.x;
    const int t = threadIdx.x;
    const int p0 = b * CAP;
    const int p1 = p0 + cnt[b];

    hist[t] = 0; hist[t + 256] = 0;
    __syncthreads();
    for (int p = p0 + t; p < p1; p += 256)
        atomicAdd(&hist[rec[p] & 511], 1);
    __syncthreads();
    int a0 = hist[2 * t], a1 = hist[2 * t + 1];
    int s = a0 + a1;
    ts[t] = s;
    __syncthreads();
    for (int off = 1; off < 256; off <<= 1) {
        int x = (t >= off) ? ts[t - off] : 0;
        __syncthreads();
        ts[t] += x;
        __syncthreads();
    }
    int run = ts[t] - s;                 // exclusive prefix over bin pairs
    cur[2 * t]     = p0 + run;
    cur[2 * t + 1] = p0 + run + a0;
    cell_beg[(size_t)b * 513 + 2 * t]     = p0 + run;
    cell_beg[(size_t)b * 513 + 2 * t + 1] = p0 + run + a0;
    if (t == 0) cell_beg[(size_t)b * 513 + 512] = p1;
    __syncthreads();
    for (int p = p0 + t; p < p1; p += 256) {
        int rv = rec[p];
        int pos = atomicAdd(&cur[rv & 511], 1);
        eidx[pos] = rv >> 9;   // src
    }
}

// ---------------------------------------------------------------------------
// Fused RGCN layer: 32 dst nodes per block (grid = 2*B).
// Phase 1 (gather): sum table rows of srcs into LDS S[node][r][64] (bf16,
//   fp32 run accumulation; runs are contiguous after the 512-cell sort so
//   each cell is owned by one half-wave -> no atomics). r=8 row = own row
//   (self-loop).
// Phase 2 (MFMA): out[node][0:H] = S[node][0:576] . Wt[576][H] via 18
//   chained 16x16x32 MFMAs per (node-group, m-tile) task. Operand-swapped
//   (verified R10 pattern): D row=quad*4+i -> h, col=lane&15 -> node.
// ---------------------------------------------------------------------------
template<int H, bool RELUOUT, bool F32OUT>
__global__ __launch_bounds__(256) void rgcn_layer(
    const unsigned int* __restrict__ tbl32,   // [N][32] packed bf16 (64 cols)
    const unsigned short* __restrict__ Wt,    // [9*H][64] bf16
    const float* __restrict__ bias,           // [H]
    const int* __restrict__ cell_beg,         // [B][513]
    const int* __restrict__ eidx,             // src, bucket-strided
    void* __restrict__ outv, int N)
{
    constexpr int SST = 584;                  // shorts per node row (576+8 pad)
    __shared__ unsigned short S[32 * SST];    // 37,376 B
    unsigned int* S32 = (unsigned int*)S;
    const int tid = threadIdx.x;
    const int b = blockIdx.x >> 1;
    const int sb = blockIdx.x & 1;
    const int base = b * 64 + sb * 32;        // first dst node of this block
    const int* cb = cell_beg + (size_t)b * 513 + sb * 256;

    // ---- Phase 1: gather-sum into S ----
    const int hw = tid >> 5, c = tid & 31;    // half-wave id, uint column
    #pragma unroll 4
    for (int i = 0; i < 32; ++i) {
        int cell = hw + 8 * i;                // [0,256)
        int beg = cb[cell], end = cb[cell + 1];
        float s0 = 0.f, s1 = 0.f;
        for (int p = beg; p < end; ++p) {
            unsigned int v = tbl32[(size_t)eidx[p] * 32 + c];
            s0 += bf2f((unsigned short)(v & 0xffff));
            s1 += bf2f((unsigned short)(v >> 16));
        }
        int node = cell >> 3, et = cell & 7;
        S32[node * (SST / 2) + et * 32 + c] =
            (unsigned int)f2bf(s0) | ((unsigned int)f2bf(s1) << 16);
    }
    // Self-loop rows (r = 8): copy own table row (zeros past N).
    #pragma unroll
    for (int t2 = 0; t2 < 4; ++t2) {
        int j = tid + t2 * 256;               // [0,1024)
        int row = j >> 5, cc = j & 31;
        int nd = base + row;
        unsigned int v = 0;
        if (nd < N) v = tbl32[(size_t)nd * 32 + cc];
        S32[row * (SST / 2) + 8 * 32 + cc] = v;
    }
    __syncthreads();

    // ---- Phase 2: MFMA over K=576 ----
    const int w = tid >> 6, lane = tid & 63;
    const int m = lane & 15, quad = lane >> 4;
    constexpr int MT = H / 16;                // m-tiles: 4 (H=64) or 2 (H=32)
    for (int task = w; task < 2 * MT; task += 4) {
        int ng = task & 1;                    // node group (16 nodes)
        int mt = task >> 1;                   // h-tile
        int nd = base + ng * 16 + m;          // this lane's node (D column)
        f32x4 acc = (f32x4){0.f, 0.f, 0.f, 0.f};
        #pragma unroll
        for (int ch = 0; ch < 18; ++ch) {
            short8 sf = *(const short8*)&S[(ng * 16 + m) * SST + ch * 32 + quad * 8];
            short8 wf = *(const short8*)
                &Wt[((size_t)((ch >> 1) * H + mt * 16 + m)) * 64 + (ch & 1) * 32 + quad * 8];
            acc = __builtin_amdgcn_mfma_f32_16x16x32_bf16(wf, sf, acc, 0, 0, 0);
        }
        float4 bv = *(const float4*)&bias[mt * 16 + quad * 4];
        if (nd < N) {
            float o0 = acc[0] + bv.x, o1 = acc[1] + bv.y;
            float o2 = acc[2] + bv.z, o3 = acc[3] + bv.w;
            if (RELUOUT) {
                o0 = fmaxf(o0, 0.f); o1 = fmaxf(o1, 0.f);
                o2 = fmaxf(o2, 0.f); o3 = fmaxf(o3, 0.f);
            }
            if constexpr (F32OUT) {
                float* out = (float*)outv;
                float4 o = make_float4(o0, o1, o2, o3);
                *(float4*)&out[(size_t)nd * H + mt * 16 + quad * 4] = o;
            } else {
                unsigned short* out = (unsigned short*)outv;
                ushort4 u;
                u.x = f2bf(o0); u.y = f2bf(o1); u.z = f2bf(o2); u.w = f2bf(o3);
                *(ushort4*)&out[(size_t)nd * H + mt * 16 + quad * 4] = u;
            }
        }
    }
}

extern "C" void kernel_launch(void* const* d_in, const int* in_sizes, int n_in,
                              void* d_out, int out_size, void* d_ws, size_t ws_size,
                              hipStream_t stream)
{
    const float* feat = (const float*)d_in[0];
    const int*   src  = (const int*)d_in[1];
    const int*   dst  = (const int*)d_in[2];
    const int*   et   = (const int*)d_in[3];
    const float* W1   = (const float*)d_in[4];
    const float* Ws1  = (const float*)d_in[5];
    const float* b1   = (const float*)d_in[6];
    const float* W2   = (const float*)d_in[7];
    const float* Ws2  = (const float*)d_in[8];
    const float* b2   = (const float*)d_in[9];
    float* out = (float*)d_out;

    const int N = in_sizes[0] / 64;           // 100000
    const int E = in_sizes[1];                // 1600000
    const int R = in_sizes[4] / (64 * 64);    // 8
    const int B = (N + 63) / 64;              // 1563 fine buckets

    // Workspace layout
    unsigned short* featb = (unsigned short*)d_ws;            // [N][64] bf16
    unsigned short* h1    = featb + (size_t)N * 64;           // [N][64] bf16
    unsigned short* Wt1   = h1 + (size_t)N * 64;              // [(R+1)*64*64]
    unsigned short* Wt2   = Wt1 + (size_t)(R + 1) * 64 * 64;  // [(R+1)*32*64]
    int* cnt      = (int*)(Wt2 + (size_t)(R + 1) * 32 * 64);  // [B]
    int* cell_beg = cnt + B;                                  // [B*513]
    int* rec      = cell_beg + (size_t)B * 513;               // [B*CAP]
    int* eidx     = rec + (size_t)B * CAP;                    // [B*CAP]

    const dim3 blk(256);
    const int P  = 128;                       // partition blocks
    const int CH = (E + P - 1) / P;           // 12500 edges per block

    // ---- Prep: weights (bf16, [r][h][d], self appended) + feat bf16 ----
    transpose_w<64><<<((R + 1) * 64 * 64 + 255) / 256, blk, 0, stream>>>(W1, Ws1, Wt1, R);
    transpose_w<32><<<((R + 1) * 32 * 64 + 255) / 256, blk, 0, stream>>>(W2, Ws2, Wt2, R);
    f32_to_bf16<<<(N * 16 + 255) / 256, blk, 0, stream>>>(feat, featb, N * 16);

    // ---- Edge index: bucket partition + 512-cell counting sort ----
    zero_int<<<(B + 255) / 256, blk, 0, stream>>>(cnt, B);
    partition_fine<<<P, blk, 0, stream>>>(src, dst, et, cnt, rec, E, N, B, CH);
    bucket_sort512<<<B, blk, 0, stream>>>(cnt, rec, eidx, cell_beg);

    // ---- Layer 1: h1 = relu(gather-sum(feat).Wcat1 + b1), bf16 ----
    rgcn_layer<64, true, false><<<2 * B, blk, 0, stream>>>(
        (const unsigned int*)featb, Wt1, b1, cell_beg, eidx, h1, N);

    // ---- Layer 2: out = gather-sum(h1).Wcat2 + b2, fp32 ----
    rgcn_layer<32, false, true><<<2 * B, blk, 0, stream>>>(
        (const unsigned int*)h1, Wt2, b2, cell_beg, eidx, out, N);
}